// Round 5
// baseline (54.955 us; speedup 1.0000x reference)
//
#include <hip/hip_runtime.h>
#include <math.h>

#define NB 32
#define NS 8192
#define ND 256
#define NP 64
#define TILE 256

// -ln(10000)/256
#define DIV_C (-0.035977892f)
#define INV2PI 0.15915494f

typedef float vf4 __attribute__((ext_vector_type(4)));

__global__ __launch_bounds__(256) void rwave_pe_kernel(
    const float* __restrict__ pe,
    const int*   __restrict__ peaks,
    const int*   __restrict__ npk,
    float*       __restrict__ out)
{
    const int b    = blockIdx.y;
    const int tile = blockIdx.x;
    const int tid  = threadIdx.x;
    const int lane = tid & 63;   // lane p owns peak p; also channel group 4*lane..4*lane+3
    const int wid  = tid >> 6;

    const int n = npk[b];

    // ---- register-resident prologue (no LDS, no barriers) ----
    const int   ipk = peaks[b * NP + lane];
    const float pk  = (float)ipk;
    // rr[p] = pk[p]-pk[p-1]; rr[0] duplicates first diff
    const float pk_prev = __shfl_up(pk, 1);
    const float pk_next = __shfl_down(pk, 1);
    float rr = (lane == 0) ? (pk_next - pk) : (pk - pk_prev);
    if (n == 1) rr = 4096.0f;                       // MAX_LEN/2
    // avg_rr = max(1, sum(valid rr)/n)
    float rrsum = (lane < n) ? rr : 0.0f;
    #pragma unroll
    for (int m = 1; m < 64; m <<= 1) rrsum += __shfl_xor(rrsum, m);
    const float avg = fmaxf(1.0f, rrsum / (float)n);

    // div_term for this lane's channel pairs j=2*lane, 2*lane+1, pre-scaled to revolutions
    const float dv0 = expf((float)(4 * lane)     * DIV_C) * INV2PI;
    const float dv1 = expf((float)(4 * lane + 2) * DIV_C) * INV2PI;

    const size_t rowBase = (size_t)b * NS + (size_t)tile * TILE;
    vf4* outv = reinterpret_cast<vf4*>(out);

    if (n > 0) {
        for (int pl = wid; pl < TILE; pl += 4) {
            const int pos = tile * TILE + pl;       // whole wave: one position
            // wave-cooperative argmin: key = (dist<<6)|laneIdx, invalid -> MAX
            const int idist = abs(pos - ipk);
            int k = (lane < n) ? ((idist << 6) | lane) : 0x7FFFFFFF;
            k = min(k, __shfl_xor(k, 1));
            k = min(k, __shfl_xor(k, 2));
            k = min(k, __shfl_xor(k, 4));
            k = min(k, __shfl_xor(k, 8));
            k = min(k, __shfl_xor(k, 16));
            k = min(k, __shfl_xor(k, 32));
            const int  best = k & 63;               // first-index tie-break preserved
            const bool ispk = (k >> 6) == 0;

            const float npos   = __shfl(pk, best);
            const float nrr0   = __shfl(rr, best);
            const float prevrr = __shfl(rr, best > 0 ? best - 1 : 0);
            const float nrr    = fmaxf(nrr0, 1.0f);
            const float rel    = ((float)pos - npos) / nrr;
            const float arel   = fabsf(rel);
            const float phase  = arel - floorf(arel);

            vf4 v;
            const float t0 = phase * dv0;
            const float t1 = phase * dv1;
            v.x = __builtin_amdgcn_sinf(t0);
            v.y = __builtin_amdgcn_cosf(t0);
            v.z = __builtin_amdgcn_sinf(t1);
            v.w = __builtin_amdgcn_cosf(t1);
            if (lane < 2) {
                if (lane == 0) {
                    // sin(pi*rel)=sin(rel/2 rev) with exact mod-1 reduction; sin/cos(2pi*phase)
                    float th = rel * 0.5f;
                    th = th - floorf(th);
                    v.x = __builtin_amdgcn_sinf(th);
                    v.y = __builtin_amdgcn_cosf(th);
                    v.z = __builtin_amdgcn_sinf(phase);
                    v.w = __builtin_amdgcn_cosf(phase);
                } else {
                    v.x = fminf(arel, 1.0f);
                    v.y = ispk ? 1.0f : 0.0f;
                    v.z = fminf(fmaxf(nrr / avg, 0.5f), 2.0f);
                    v.w = (best > 0) ? fminf(fabsf(nrr - prevrr) / avg, 1.0f) : 0.0f;
                }
            }
            outv[(rowBase + (size_t)pl) * (ND / 4) + lane] = v;
        }
    } else {
        // empty-peak fallback: copy pe rows (setup guarantees n>=8; kept for fidelity)
        const vf4* pev = reinterpret_cast<const vf4*>(pe);
        for (int pl = wid; pl < TILE; pl += 4) {
            vf4 v = pev[((size_t)tile * TILE + (size_t)pl) * (ND / 4) + lane];
            outv[(rowBase + (size_t)pl) * (ND / 4) + lane] = v;
        }
    }
}

extern "C" void kernel_launch(void* const* d_in, const int* in_sizes, int n_in,
                              void* d_out, int out_size, void* d_ws, size_t ws_size,
                              hipStream_t stream) {
    (void)in_sizes; (void)n_in; (void)d_ws; (void)ws_size; (void)out_size;
    const float* pe    = (const float*)d_in[1];
    const int*   peaks = (const int*)d_in[2];
    const int*   npk   = (const int*)d_in[3];
    float*       out   = (float*)d_out;

    dim3 grid(NS / TILE, NB);
    rwave_pe_kernel<<<grid, 256, 0, stream>>>(pe, peaks, npk, out);
}

// Round 6
// 46.660 us; speedup vs baseline: 1.1778x; 1.1778x over previous
//
#include <hip/hip_runtime.h>
#include <math.h>

#define NB 32
#define NS 8192
#define ND 256
#define NP 64
#define TILE 128

// -ln(10000)/256
#define DIV_C (-0.035977892f)
#define INV2PI 0.15915494f

typedef float vf4 __attribute__((ext_vector_type(4)));

__global__ __launch_bounds__(256) void rwave_pe_kernel(
    const float* __restrict__ pe,
    const int*   __restrict__ peaks,
    const int*   __restrict__ npk,
    float*       __restrict__ out)
{
    const int b    = blockIdx.y;
    const int tile = blockIdx.x;
    const int tid  = threadIdx.x;

    __shared__ float s_pk[NP];
    __shared__ float s_rr[NP];
    // [0..7] = special channels 0..7, [8] = phase.  Stride 9 (odd) -> conflict-free writes.
    __shared__ float s_scal[TILE][9];

    const int n = npk[b];

    if (tid < NP) s_pk[tid] = (float)peaks[b * NP + tid];
    __syncthreads();
    if (tid < NP) {
        float rrv;
        if (n == 1)        rrv = 4096.0f;                     // MAX_LEN/2
        else if (tid == 0) rrv = s_pk[1] - s_pk[0];
        else               rrv = s_pk[tid] - s_pk[tid - 1];
        s_rr[tid] = rrv;
    }
    __syncthreads();

    if (n > 0 && tid < TILE) {
        const float posf = (float)(tile * TILE + tid);
        int   best  = 0;
        float bestd = INFINITY;
        float rrsum = 0.0f;
        bool  ispk  = false;
        for (int p = 0; p < n; ++p) {
            float d = fabsf(posf - s_pk[p]);
            if (d < bestd) { bestd = d; best = p; }
            ispk = ispk || (d == 0.0f);
            rrsum += s_rr[p];
        }
        const float avg   = fmaxf(1.0f, rrsum / (float)n);
        const float nrr   = fmaxf(s_rr[best], 1.0f);
        const float npos  = s_pk[best];
        const float rel   = (posf - npos) / nrr;
        const float arel  = fabsf(rel);
        const float phase = arel - floorf(arel);
        const float prevrr = s_rr[best > 0 ? best - 1 : 0];

        // channels 0..3: sin(pi*rel), cos(pi*rel), sin(2pi*phase), cos(2pi*phase)
        // v_sin/v_cos take revolutions: pi*rel rad = rel/2 rev; 2pi*phase rad = phase rev.
        float th = rel * 0.5f;                 // exact (mul by power of 2)
        th = th - floorf(th);                  // exact reduction mod 1 revolution
        s_scal[tid][0] = __builtin_amdgcn_sinf(th);
        s_scal[tid][1] = __builtin_amdgcn_cosf(th);
        s_scal[tid][2] = __builtin_amdgcn_sinf(phase);
        s_scal[tid][3] = __builtin_amdgcn_cosf(phase);
        s_scal[tid][4] = fminf(arel, 1.0f);
        s_scal[tid][5] = ispk ? 1.0f : 0.0f;
        s_scal[tid][6] = fminf(fmaxf(nrr / avg, 0.5f), 2.0f);
        s_scal[tid][7] = (best > 0) ? fminf(fabsf(nrr - prevrr) / avg, 1.0f) : 0.0f;
        s_scal[tid][8] = phase;
    }
    __syncthreads();

    const int lane = tid & 63;   // channel group: channels 4*lane .. 4*lane+3
    const int wid  = tid >> 6;   // wave id

    // div_term[k] = exp(2k * -ln(10000)/256); this lane uses k0=2*lane, k1=2*lane+1.
    // Pre-scale by 1/(2*pi): hardware v_sin/v_cos take revolutions.
    const float dv0 = expf((float)(4 * lane)     * DIV_C) * INV2PI;
    const float dv1 = expf((float)(4 * lane + 2) * DIV_C) * INV2PI;

    const size_t rowBase = (size_t)b * NS + (size_t)tile * TILE;
    vf4* outv = reinterpret_cast<vf4*>(out);

    for (int pl = wid; pl < TILE; pl += 4) {
        vf4 v;
        if (n > 0) {
            const float ph = s_scal[pl][8];
            const float t0 = ph * dv0;
            const float t1 = ph * dv1;
            v.x = __builtin_amdgcn_sinf(t0);
            v.y = __builtin_amdgcn_cosf(t0);
            v.z = __builtin_amdgcn_sinf(t1);
            v.w = __builtin_amdgcn_cosf(t1);
            if (lane < 2) {                    // short LDS-only override, no trans
                const int base = 4 * lane;
                v.x = s_scal[pl][base + 0];
                v.y = s_scal[pl][base + 1];
                v.z = s_scal[pl][base + 2];
                v.w = s_scal[pl][base + 3];
            }
        } else {
            // empty-peak fallback: copy pe[s]
            const vf4* pev = reinterpret_cast<const vf4*>(pe);
            v = pev[((size_t)tile * TILE + (size_t)pl) * (ND / 4) + lane];
        }
        outv[(rowBase + (size_t)pl) * (ND / 4) + lane] = v;
    }
}

extern "C" void kernel_launch(void* const* d_in, const int* in_sizes, int n_in,
                              void* d_out, int out_size, void* d_ws, size_t ws_size,
                              hipStream_t stream) {
    (void)in_sizes; (void)n_in; (void)d_ws; (void)ws_size; (void)out_size;
    const float* pe    = (const float*)d_in[1];
    const int*   peaks = (const int*)d_in[2];
    const int*   npk   = (const int*)d_in[3];
    float*       out   = (float*)d_out;

    dim3 grid(NS / TILE, NB);
    rwave_pe_kernel<<<grid, 256, 0, stream>>>(pe, peaks, npk, out);
}